// Round 6
// baseline (26.550 us; speedup 1.0000x reference)
//
#include <hip/hip_runtime.h>

// CTC forward loss, B=512, T=512, C=81 (blank=80), L=64.
// One BLOCK (128 thr = 2 waves) per batch element.
//   wave0: forward alpha over t=0..255   (alpha_t = D(q_t) A alpha_{t-1})
//   wave1: backward gamma over t=511..256 (gamma^T = f^T prod D(q_t) A)
//   ll = sum_s gamma[s]*alpha[s]  (combined via LDS after barrier)
// Lane l holds states 2l, 2l+1 (+ s=128 on lane 63). LINEAR-domain f64 with
// exact power-of-2 Rabiner rescale every 32 steps (int-hi-word DPP max tree).
// Invalid states (s>2len) held at exactly 0 by masking the odd state with
// (lane<len). Cross-lane via DPP wave_shr:1 / wave_shl:1 (pure VALU).
// Prefetch: 4 rotating chunks of 8 rows; per chunk 9 loads: 8 per-lane label
// gathers + ONE blank load (lane l -> row (l&7) blank, consumed by readlane).
// Counted vmcnt(18) waits (2-chunk lead). amdgpu_waves_per_eu(1,2) pins the
// regalloc occupancy target so the buffers stay in VGPRs (r2/r5 spill fix).

#define TSTEPS 512
#define NCLS   81
#define ROWB   324
#define LMAX   64
#define PADTOK 99
#define EPSF   1e-7f
#define UU     8
#define CHB    (UU * ROWB)

#if __has_builtin(__builtin_amdgcn_logf)
#define FLOG2 __builtin_amdgcn_logf
#else
#define FLOG2 log2f
#endif

__device__ __forceinline__ double dpp_shr1_f64(double x) {   // lane l <- l-1, lane0 -> 0
  unsigned long long u = __builtin_bit_cast(unsigned long long, x);
  int lo = __builtin_amdgcn_update_dpp(0, (int)u,         0x138, 0xF, 0xF, true);
  int hi = __builtin_amdgcn_update_dpp(0, (int)(u >> 32), 0x138, 0xF, 0xF, true);
  unsigned long long r = ((unsigned long long)(unsigned)hi << 32) | (unsigned)lo;
  return __builtin_bit_cast(double, r);
}
__device__ __forceinline__ double dpp_shl1_f64(double x) {   // lane l <- l+1, lane63 -> 0
  unsigned long long u = __builtin_bit_cast(unsigned long long, x);
  int lo = __builtin_amdgcn_update_dpp(0, (int)u,         0x130, 0xF, 0xF, true);
  int hi = __builtin_amdgcn_update_dpp(0, (int)(u >> 32), 0x130, 0xF, 0xF, true);
  unsigned long long r = ((unsigned long long)(unsigned)hi << 32) | (unsigned)lo;
  return __builtin_bit_cast(double, r);
}
template <int CTRL>
__device__ __forceinline__ int dppmaxi(int x) {
  int y = __builtin_amdgcn_update_dpp(0, x, CTRL, 0xF, 0xF, true);
  return x > y ? x : y;
}
__device__ __forceinline__ double andm(double x, long long m) {
  return __builtin_bit_cast(double, __builtin_bit_cast(long long, x) & m);
}
__device__ __forceinline__ float rlanef(float v, int k) {   // k compile-time
  return __builtin_bit_cast(float,
      __builtin_amdgcn_readlane(__builtin_bit_cast(int, v), k));
}

#define GL(dst, p, OFF) \
  asm volatile("global_load_dword %0, %1, off offset:" #OFF : "=v"(dst) : "v"(p))

// 9 loads per chunk: 1 blank (lane l -> row l&7), 8 label gathers
#define LOADBODY(BV, LV) \
    GL(BV,    pbp, 0); \
    GL(LV[0], plp, 0); \
    GL(LV[1], plp, 324); \
    GL(LV[2], plp, 648); \
    GL(LV[3], plp, 972); \
    GL(LV[4], plp, 1296); \
    GL(LV[5], plp, 1620); \
    GL(LV[6], plp, 1944); \
    GL(LV[7], plp, 2268);

#define LOADCF(BV, LV) do { LOADBODY(BV, LV) pbp += CHB; plp += CHB; } while (0)
#define LOADCB(BV, LV) do { LOADBODY(BV, LV) pbp -= CHB; plp -= CHB; } while (0)

#define WAITV(N) asm volatile("s_waitcnt vmcnt(" #N ")" ::: "memory")

#define PIN(BV, LV) \
  asm volatile("" : "+v"(BV), \
                    "+v"(LV[0]), "+v"(LV[1]), "+v"(LV[2]), "+v"(LV[3]), \
                    "+v"(LV[4]), "+v"(LV[5]), "+v"(LV[6]), "+v"(LV[7]))

// ---- forward step (verified r4/r5); a2 unconditional (==0 unless len==64)
#define STEPF(qbf, plv) do { \
    const double qb  = (double)((qbf) + EPSF); \
    const double ql  = (double)((plv) + EPSF); \
    const double a1u = dpp_shr1_f64(a1); \
    const double a3  = andm(a1u, allowm); \
    const double n0  = (a0 + a1u) * qb; \
    const double n1  = andm(((a1 + a0) + a3) * ql, validm); \
    a2 = (a2 + a1) * qb; \
    a0 = n0; a1 = n1; \
  } while (0)

// ---- backward step (verified r5)
#define STEPB(qbf, plv) do { \
    const double qb = (double)((qbf) + EPSF); \
    const double ql = (double)((plv) + EPSF); \
    const double d0 = g0 * qb; \
    const double d1 = g1 * ql; \
    const double d2 = g2 * qb; \
    const double s0 = dpp_shl1_f64(d0); \
    const double s1 = dpp_shl1_f64(d1); \
    const double t1 = (d1 + (s0 + andm(d2, l63m))) + andm(s1, am_next); \
    g1 = andm(t1, validm); \
    g0 = d0 + d1; \
    g2 = d2; \
  } while (0)

#define COMPF(BV, LV) do { \
    _Pragma("unroll") \
    for (int u = 0; u < UU; ++u) STEPF(rlanef(BV, u), LV[u]); } while (0)
#define COMPB(BV, LV) do { \
    _Pragma("unroll") \
    for (int u = UU - 1; u >= 0; --u) STEPB(rlanef(BV, u), LV[u]); } while (0)

// exact 2^k rescale; k from wave-max hi-word exponent (values all >= 0)
#define RESCALE3(x, y, z, E) do { \
    double mx = fmax(fmax(x, y), z); \
    int mh = (int)(__builtin_bit_cast(unsigned long long, mx) >> 32); \
    mh = dppmaxi<0x111>(mh); \
    mh = dppmaxi<0x112>(mh); \
    mh = dppmaxi<0x114>(mh); \
    mh = dppmaxi<0x118>(mh); \
    mh = dppmaxi<0x142>(mh); \
    mh = dppmaxi<0x143>(mh); \
    const int hb = __builtin_amdgcn_readlane(mh, 63); \
    const int ef = (hb >> 20) & 0x7FF; \
    const double sc = __builtin_bit_cast(double, \
                        (unsigned long long)(2046 - ef) << 52); \
    x *= sc; y *= sc; z *= sc; \
    E += ef - 1023; \
  } while (0)

// 32-chunk pipeline: 2 chunks in flight beyond current, counted vmcnt,
// rescale every 4 chunks (32 steps)
#define DRIVER(LOADM, COMPM, INITM, RESCM) do { \
    LOADM(bvA, lvA); LOADM(bvB, lvB); LOADM(bvC, lvC); \
    WAITV(18); PIN(bvA, lvA); LOADM(bvD, lvD); INITM; \
    WAITV(18); PIN(bvB, lvB); LOADM(bvA, lvA); COMPM(bvB, lvB); \
    WAITV(18); PIN(bvC, lvC); LOADM(bvB, lvB); COMPM(bvC, lvC); \
    WAITV(18); PIN(bvD, lvD); LOADM(bvC, lvC); COMPM(bvD, lvD); RESCM; \
    _Pragma("unroll 1") \
    for (int i = 1; i < 7; ++i) { \
      WAITV(18); PIN(bvA, lvA); LOADM(bvD, lvD); COMPM(bvA, lvA); \
      WAITV(18); PIN(bvB, lvB); LOADM(bvA, lvA); COMPM(bvB, lvB); \
      WAITV(18); PIN(bvC, lvC); LOADM(bvB, lvB); COMPM(bvC, lvC); \
      WAITV(18); PIN(bvD, lvD); LOADM(bvC, lvC); COMPM(bvD, lvD); RESCM; \
    } \
    WAITV(18); PIN(bvA, lvA); LOADM(bvD, lvD); COMPM(bvA, lvA); \
    WAITV(18); PIN(bvB, lvB); COMPM(bvB, lvB); \
    WAITV(9);  PIN(bvC, lvC); COMPM(bvC, lvC); \
    WAITV(0);  PIN(bvD, lvD); COMPM(bvD, lvD); RESCM; \
  } while (0)

#define INITF do { \
    a0 = lane0 ? (double)(rlanef(bvA, 0) + EPSF) : 0.0; \
    a1 = lane0 ? (double)(lvA[0] + EPSF) : 0.0; \
    a2 = 0.0; \
    _Pragma("unroll") \
    for (int u = 1; u < UU; ++u) STEPF(rlanef(bvA, u), lvA[u]); \
  } while (0)

#define INITB do { \
    g0 = (lane == len)     ? 1.0 : 0.0;    /* s=2len (lane<64 since len<64 here or g2 path) */ \
    g1 = (lane == len - 1) ? 1.0 : 0.0;    /* s=2len-1 */ \
    g2 = (full && lane == 63) ? 1.0 : 0.0; /* s=128 when len==64 */ \
    _Pragma("unroll") \
    for (int u = UU - 1; u >= 0; --u) STEPB(rlanef(bvA, u), lvA[u]); \
  } while (0)

__global__ void __launch_bounds__(128)
__attribute__((amdgpu_waves_per_eu(1, 2)))
ctc_kernel(const int* __restrict__ y_true, const float* __restrict__ y_pred,
           float* __restrict__ out)
{
  const int b    = blockIdx.x;
  const int tid  = threadIdx.x;
  const int lane = tid & 63;
  const int wv   = tid >> 6;
  const char* yp = (const char*)(y_pred + (size_t)b * (TSTEPS * NCLS));

  const int  yt  = y_true[b * LMAX + lane];
  const bool mk  = (yt != PADTOK);
  const int  len = __popcll(__ballot(mk));
  const int  lab = mk ? yt : 0;
  const int  labu   = __shfl_up(lab, 1);
  const int  allowi = ((lane >= 1) && (lab != labu)) ? 1 : 0;
  const int  allown = __shfl_down(allowi, 1);
  const long long allowm  = allowi ? -1LL : 0LL;
  const long long am_next = allown ? -1LL : 0LL;
  const long long validm  = (lane < len) ? -1LL : 0LL;
  const long long l63m    = (lane == 63) ? -1LL : 0LL;
  const bool lane0 = (lane == 0);
  const bool full  = (len == LMAX);

  __shared__ double sh[129];
  __shared__ int    shE;

  double a0, a1, a2;          // forward states
  double g0, g1, g2;          // backward states
  int Ef = 0, Eb = 0;
  float bvA, bvB, bvC, bvD;                  // blank: lane l holds row (l&7)
  float lvA[UU], lvB[UU], lvC[UU], lvD[UU];  // label gathers, per-lane

  if (wv == 0) {
    // forward: rows 0..255
    const char* pbp = yp + (lane & 7) * ROWB + 320;
    const char* plp = yp + lab * 4;
    DRIVER(LOADCF, COMPF, INITF, RESCALE3(a0, a1, a2, Ef));
    sh[lane]      = a0;
    sh[64 + lane] = a1;
    if (lane == 63) sh[128] = a2;
    if (lane0)      shE     = Ef;
  } else {
    // backward: rows 511..256 (chunk base row 504, descending)
    const char* pbp = yp + (504 + (lane & 7)) * ROWB + 320;
    const char* plp = yp + 504 * ROWB + lab * 4;
    DRIVER(LOADCB, COMPB, INITB, RESCALE3(g0, g1, g2, Eb));
  }

  __syncthreads();

  if (wv == 1) {
    double p = g0 * sh[lane] + g1 * sh[64 + lane];
    p += andm(g2 * sh[128], l63m);
#pragma unroll
    for (int off = 32; off; off >>= 1) p += __shfl_xor(p, off);
    if (lane0) {
      const unsigned long long sb = __builtin_bit_cast(unsigned long long, p);
      const int    e2   = (int)((sb >> 52) & 0x7FF) - 1023;
      const double mant = __builtin_bit_cast(double,
          (sb & 0x000FFFFFFFFFFFFFULL) | 0x3FF0000000000000ULL);
      const float  ll2  = FLOG2((float)mant) + (float)(e2 + Eb + shE);
      out[b] = -ll2 * 0.69314718055994530942f;
    }
  }
}

extern "C" void kernel_launch(void* const* d_in, const int* in_sizes, int n_in,
                              void* d_out, int out_size, void* d_ws, size_t ws_size,
                              hipStream_t stream) {
  const int*   y_true = (const int*)d_in[0];
  const float* y_pred = (const float*)d_in[1];
  float*       out    = (float*)d_out;
  hipLaunchKernelGGL(ctc_kernel, dim3(512), dim3(128), 0, stream,
                     y_true, y_pred, out);
}